// Round 10
// baseline (864.340 us; speedup 1.0000x reference)
//
#include <hip/hip_runtime.h>

typedef unsigned short u16;
typedef unsigned int u32;
typedef __attribute__((ext_vector_type(8))) short bf16x8;
typedef __attribute__((ext_vector_type(4))) float f32x4;
typedef __attribute__((ext_vector_type(16))) float f32x16;

#define NB 16
#define NC 256
#define NL 2048
#define EPS 1e-5f
#define QSC2 0.0901684401f   // (1/sqrt(256)) * log2(e)
#define DEFER 11.54f         // 8 * log2(e)
#define TROWS 2050
#define PHALF ((size_t)NB * NC * NL)

__device__ __forceinline__ float bf2f(u16 a) {
  union { unsigned u; float f; } v; v.u = (unsigned)a << 16; return v.f;
}
__device__ __forceinline__ u16 f2bf(float f) {
  union { float f; unsigned u; } v; v.f = f;
  return (u16)((v.u + 0x7fffu + ((v.u >> 16) & 1u)) >> 16);
}
__device__ __forceinline__ u32 cvtpk(float lo, float hi) {
  u32 r;
  asm("v_cvt_pk_bf16_f32 %0, %1, %2" : "=v"(r) : "v"(lo), "v"(hi));
  return r;
}
__device__ __forceinline__ float ex2(float x) {
  float r;
  asm("v_exp_f32 %0, %1" : "=v"(r) : "v"(x));
  return r;
}
__device__ __forceinline__ void gld16(const void* gsrc, void* ldst) {
  __builtin_amdgcn_global_load_lds(
      (const __attribute__((address_space(1))) void*)gsrc,
      (__attribute__((address_space(3))) void*)ldst, 16, 0, 0);
}

// ---------------- weight pack ----------------
__global__ __launch_bounds__(256)
void pack_w(const float* __restrict__ w1, const float* __restrict__ w2,
            const float* __restrict__ w3, const float* __restrict__ w4,
            const float* __restrict__ lw, const float* __restrict__ lb,
            u16* __restrict__ Wp, u16* __restrict__ Wq, float* __restrict__ bq)
{
  const int a = blockIdx.y;
  const int gid = blockIdx.x * 256 + threadIdx.x;
  if (a < 4) {
    const float* w = a == 0 ? w1 : a == 1 ? w2 : a == 2 ? w3 : w4;
    const int d = gid >> 16, rem = gid & 65535;
    const int oc = rem >> 8, ic = rem & 255;
    Wp[a * 196608 + gid] = f2bf(w[(oc * 256 + ic) * 3 + d]);
  } else {
    const int oc = gid >> 8;
    const float s = (oc >= 256 && oc < 512) ? QSC2 : 1.0f;
    Wq[gid] = f2bf(lw[gid] * s);
    if (gid < 768) bq[gid] = lb[gid] * ((gid >= 256 && gid < 512) ? QSC2 : 1.0f);
  }
}

// ---------------- GN stats: fp32 (C,L) -> pstat[b*256+c] ----
__global__ __launch_bounds__(256)
void stats_f32(const float* __restrict__ x, float2* __restrict__ pstat)
{
  const int blk = blockIdx.x;
  const float* p = x + (size_t)blk * NL + threadIdx.x * 8;
  const float4 a = ((const float4*)p)[0];
  const float4 c4 = ((const float4*)p)[1];
  float s = (a.x + a.y) + (a.z + a.w) + (c4.x + c4.y) + (c4.z + c4.w);
  float ss = a.x*a.x + a.y*a.y + a.z*a.z + a.w*a.w + c4.x*c4.x + c4.y*c4.y + c4.z*c4.z + c4.w*c4.w;
#pragma unroll
  for (int o = 32; o > 0; o >>= 1) { s += __shfl_down(s, o); ss += __shfl_down(ss, o); }
  __shared__ float2 red[4];
  if ((threadIdx.x & 63) == 0) red[threadIdx.x >> 6] = make_float2(s, ss);
  __syncthreads();
  if (threadIdx.x == 0)
    pstat[blk] = make_float2(red[0].x + red[1].x + red[2].x + red[3].x,
                             red[0].y + red[1].y + red[2].y + red[3].y);
}

// ---------------- GN stats: bf16 T, partial chunks -> pstat[(b*16+chunk)*256+c] ----
__global__ __launch_bounds__(256)
void stats_T(const u16* __restrict__ inT, float2* __restrict__ pstat)
{
  const int chunk = blockIdx.x, b = blockIdx.y;
  const int t = threadIdx.x;
  const int c4 = (t & 63) * 4;
  float s[4] = {0.f, 0.f, 0.f, 0.f}, ss[4] = {0.f, 0.f, 0.f, 0.f};
  for (int j = 0; j < 32; ++j) {
    const int row = chunk * 128 + j * 4 + (t >> 6);
    const ushort4 h = *(const ushort4*)(inT + ((size_t)b * TROWS + 1 + row) * 256 + c4);
    const float v0 = bf2f(h.x), v1 = bf2f(h.y), v2 = bf2f(h.z), v3 = bf2f(h.w);
    s[0] += v0; ss[0] += v0 * v0;
    s[1] += v1; ss[1] += v1 * v1;
    s[2] += v2; ss[2] += v2 * v2;
    s[3] += v3; ss[3] += v3 * v3;
  }
  __shared__ float2 srs[256][4];
#pragma unroll
  for (int i = 0; i < 4; ++i) srs[t][i] = make_float2(s[i], ss[i]);
  __syncthreads();
  if (t < 64) {
#pragma unroll
    for (int r = 1; r < 4; ++r)
#pragma unroll
      for (int i = 0; i < 4; ++i) {
        s[i] += srs[t + 64 * r][i].x;
        ss[i] += srs[t + 64 * r][i].y;
      }
#pragma unroll
    for (int i = 0; i < 4; ++i)
      pstat[((size_t)b * 16 + chunk) * 256 + t * 4 + i] = make_float2(s[i], ss[i]);
  }
}

// ---------------- GN apply: fp32 (C,L) -> bf16 T padded (bank-aware transpose) ----
__global__ __launch_bounds__(256)
void apply_f32T(const float* __restrict__ x, const float2* __restrict__ pstat,
                const float* __restrict__ gw, const float* __restrict__ gb,
                u16* __restrict__ outT)
{
  __shared__ float2 chs[256];
  __shared__ float gm[32], gi[32];
  __shared__ float ta[32][257];   // l-major: banks <=2-way both sides
  const int t = threadIdx.x, b = blockIdx.y;
  const int L0 = blockIdx.x * 32;
  chs[t] = pstat[b * 256 + t];
  __syncthreads();
  if (t < 32) {
    float S = 0.f, SS = 0.f;
#pragma unroll
    for (int j = 0; j < 8; ++j) { S += chs[t * 8 + j].x; SS += chs[t * 8 + j].y; }
    const float mean = S * (1.f / 16384.f);
    const float var = SS * (1.f / 16384.f) - mean * mean;
    gm[t] = mean; gi[t] = rsqrtf(var + EPS);
  }
  {
    const int cR = t >> 3, lq = (t & 7) * 4;
#pragma unroll
    for (int i = 0; i < 8; ++i) {
      const int c = i * 32 + cR;
      const float4 v = *(const float4*)&x[((size_t)b * NC + c) * NL + L0 + lq];
      ta[lq + 0][c] = v.x; ta[lq + 1][c] = v.y; ta[lq + 2][c] = v.z; ta[lq + 3][c] = v.w;
    }
  }
  __syncthreads();
  const int g = t & 31, rbase = t >> 5;
  float ga[8], be[8];
#pragma unroll
  for (int j = 0; j < 4; ++j)
#pragma unroll
    for (int k = 0; k < 2; ++k) {
      const int c = 2 * g + 64 * j + k;
      const int grp = c >> 3;
      ga[j * 2 + k] = gw[c] * gi[grp];
      be[j * 2 + k] = gb[c] - gm[grp] * ga[j * 2 + k];
    }
#pragma unroll
  for (int ri = 0; ri < 4; ++ri) {
    const int row = rbase + ri * 8;
    u16* orow = outT + ((size_t)b * TROWS + 1 + L0 + row) * 256;
#pragma unroll
    for (int j = 0; j < 4; ++j) {
      const int c = 2 * g + 64 * j;
      const float v0 = ta[row][c], v1 = ta[row][c + 1];
      ushort2 o;
      o.x = f2bf(fmaxf(fmaf(v0, ga[j * 2], be[j * 2]), 0.f));
      o.y = f2bf(fmaxf(fmaf(v1, ga[j * 2 + 1], be[j * 2 + 1]), 0.f));
      *(ushort2*)(orow + c) = o;
    }
  }
  if (blockIdx.x == 0 && t < 128) {
    const int r = (t >> 6) ? 2049 : 0;
    *(ushort4*)(outT + ((size_t)b * TROWS + r) * 256 + (t & 63) * 4) = (ushort4){0, 0, 0, 0};
  }
}

// ---------------- GN apply: bf16 T -> bf16 T padded ----
__global__ __launch_bounds__(256)
void apply_TT(const u16* __restrict__ inT, const float2* __restrict__ pstat,
              const float* __restrict__ gw, const float* __restrict__ gb,
              u16* __restrict__ outT)
{
  __shared__ float2 chs[256];
  __shared__ float gm[32], gi[32];
  const int t = threadIdx.x, b = blockIdx.y;
  {
    float S = 0.f, SS = 0.f;
#pragma unroll
    for (int p = 0; p < 16; ++p) {
      const float2 v = pstat[((size_t)b * 16 + p) * 256 + t];
      S += v.x; SS += v.y;
    }
    chs[t] = make_float2(S, SS);
  }
  __syncthreads();
  if (t < 32) {
    float S = 0.f, SS = 0.f;
#pragma unroll
    for (int j = 0; j < 8; ++j) { S += chs[t * 8 + j].x; SS += chs[t * 8 + j].y; }
    const float mean = S * (1.f / 16384.f);
    const float var = SS * (1.f / 16384.f) - mean * mean;
    gm[t] = mean; gi[t] = rsqrtf(var + EPS);
  }
  __syncthreads();
  const int g = t & 31;
  float ga[8], be[8];
#pragma unroll
  for (int j = 0; j < 8; ++j) {
    ga[j] = gw[g * 8 + j] * gi[g];
    be[j] = gb[g * 8 + j] - gm[g] * ga[j];
  }
#pragma unroll
  for (int j = 0; j < 16; ++j) {
    const int row = blockIdx.x * 128 + j * 8 + (t >> 5);
    const size_t off = ((size_t)b * TROWS + 1 + row) * 256 + g * 8;
    const bf16x8 h = *(const bf16x8*)(inT + off);
    u16 o[8];
#pragma unroll
    for (int i = 0; i < 8; ++i)
      o[i] = f2bf(fmaxf(fmaf(bf2f(((const u16*)&h)[i]), ga[i], be[i]), 0.f));
    *(bf16x8*)(outT + off) = *(bf16x8*)o;
  }
  if (blockIdx.x == 0 && t < 128) {
    const int r = (t >> 6) ? 2049 : 0;
    *(ushort4*)(outT + ((size_t)b * TROWS + r) * 256 + (t & 63) * 4) = (ushort4){0, 0, 0, 0};
  }
}

// ---------------- conv GEMM via MFMA (unchanged from r9) ----------------
template<int OCT, int KD, bool HAS_T, int RESM>
__global__ __launch_bounds__(256, 2)
void conv_mfma(const u16* __restrict__ xT, const u16* __restrict__ Wp,
               const float* __restrict__ bias, const float* __restrict__ tadd,
               u16* __restrict__ outT, u16* __restrict__ vTout,
               const float* __restrict__ resf, float* __restrict__ outf)
{
  constexpr int DOFF = (KD == 3) ? 0 : 1;
  __shared__ __align__(16) u16 xs[2][130 * 128];
  const int lb = blockIdx.x * 128;
  const int ocb = blockIdx.y * 128;
  const int b = blockIdx.z;
  const int tid = threadIdx.x;
  const int w = tid >> 6, lane = tid & 63;
  const int l15 = lane & 15, lg = lane >> 4;
  const int woc = (w >> 1) * 64, wl = (w & 1) * 64;

  f32x4 acc[4][4];
#pragma unroll
  for (int i = 0; i < 4; ++i)
#pragma unroll
    for (int j = 0; j < 4; ++j) acc[i][j] = (f32x4){0.f, 0.f, 0.f, 0.f};

  const u16* xTb = xT + ((size_t)b * TROWS + lb) * 256;

  auto stageX = [&](int buf, int ich) {
    u16* xb = &xs[buf][0];
#pragma unroll
    for (int j = 0; j < 8; ++j) {
      const int slot = w * 512 + j * 64 + lane;
      const int row = slot >> 4, g0 = slot & 15;
      const int g = (g0 & 8) | ((g0 ^ row) & 7);
      gld16(xTb + (size_t)row * 256 + ich * 128 + g * 8, xb + (size_t)(w * 512 + j * 64) * 8);
    }
    if (w == 0 && lane < 32) {
      const int slot = 2048 + lane;
      const int row = slot >> 4, g0 = slot & 15;
      const int g = (g0 & 8) | ((g0 ^ row) & 7);
      gld16(xTb + (size_t)row * 256 + ich * 128 + g * 8, xb + (size_t)2048 * 8);
    }
  };
  auto loadW = [&](bf16x8 (&af)[KD][4], int p) {
    const int ich = p >> 2, kc = p & 3;
#pragma unroll
    for (int d = 0; d < KD; ++d)
#pragma unroll
      for (int mf = 0; mf < 4; ++mf)
        af[d][mf] = *(const bf16x8*)(Wp + ((size_t)d * OCT + ocb + woc + mf * 16 + l15) * 256
                                        + ich * 128 + kc * 32 + lg * 8);
  };

  bf16x8 afbuf[2][KD][4];
  stageX(0, 0);
  loadW(afbuf[0], 0);
  __syncthreads();
  stageX(1, 1);

#pragma unroll
  for (int p = 0; p < 8; ++p) {
    if (p == 4) __syncthreads();
    if (p < 7) loadW(afbuf[(p + 1) & 1], p + 1);
    const int kc = p & 3;
    const int gg = kc * 4 + lg;
    const char* xb = (const char*)&xs[p >> 2][0];
#pragma unroll
    for (int nf = 0; nf < 4; ++nf) {
#pragma unroll
      for (int d = 0; d < KD; ++d) {
        const int r = wl + nf * 16 + l15 + d + DOFF;
        const int gsr = (gg & 8) | ((gg ^ r) & 7);
        const bf16x8 bf = *(const bf16x8*)(xb + r * 256 + gsr * 16);
#pragma unroll
        for (int mf = 0; mf < 4; ++mf)
          acc[mf][nf] = __builtin_amdgcn_mfma_f32_16x16x32_bf16(afbuf[p & 1][d][mf], bf, acc[mf][nf], 0, 0, 0);
      }
    }
  }

  if (OCT == 768 && ocb >= 512) {
    __syncthreads();
    u16* tile = (u16*)&xs[0][0];   // [128][136]
#pragma unroll
    for (int mf = 0; mf < 4; ++mf) {
      const int cl = woc + mf * 16 + lg * 4;
      const float4 bv = *(const float4*)&bias[ocb + cl];
#pragma unroll
      for (int nf = 0; nf < 4; ++nf) {
        const int ll = wl + nf * 16 + l15;
        const f32x4 a = acc[mf][nf];
        tile[(cl + 0) * 136 + ll] = f2bf(a[0] + bv.x);
        tile[(cl + 1) * 136 + ll] = f2bf(a[1] + bv.y);
        tile[(cl + 2) * 136 + ll] = f2bf(a[2] + bv.z);
        tile[(cl + 3) * 136 + ll] = f2bf(a[3] + bv.w);
      }
    }
    __syncthreads();
    const int cv0 = ocb - 512;
#pragma unroll
    for (int it = 0; it < 8; ++it) {
      const int chunk = it * 256 + tid;
      const int row = chunk >> 4, off = (chunk & 15) * 8;
      const bf16x8 v = *(const bf16x8*)&tile[row * 136 + off];
      *(bf16x8*)(vTout + ((size_t)b * NC + cv0 + row) * NL + lb + off) = v;
    }
    return;
  }

#pragma unroll
  for (int mf = 0; mf < 4; ++mf) {
    const int ocbase = ocb + woc + mf * 16 + lg * 4;
    float4 bv = *(const float4*)&bias[ocbase];
    if (HAS_T) {
      const float4 tv = *(const float4*)&tadd[b * 256 + ocbase];
      bv.x += tv.x; bv.y += tv.y; bv.z += tv.z; bv.w += tv.w;
    }
#pragma unroll
    for (int nf = 0; nf < 4; ++nf) {
      const int l = lb + wl + nf * 16 + l15;
      const f32x4 a = acc[mf][nf];
      float v0 = a[0] + bv.x, v1 = a[1] + bv.y, v2 = a[2] + bv.z, v3 = a[3] + bv.w;
      if (RESM >= 1) {
        const float* rp = resf + ((size_t)b * NC + ocbase) * NL + l;
        v0 += rp[0]; v1 += rp[NL]; v2 += rp[2 * (size_t)NL]; v3 += rp[3 * (size_t)NL];
      }
      if (RESM == 2) {
        float* op = outf + ((size_t)b * NC + ocbase) * NL + l;
        op[0] = v0; op[NL] = v1; op[2 * (size_t)NL] = v2; op[3 * (size_t)NL] = v3;
      } else if (OCT == 256) {
        ushort4 st = {f2bf(v0), f2bf(v1), f2bf(v2), f2bf(v3)};
        *(ushort4*)(outT + ((size_t)b * TROWS + 1 + l) * 256 + ocbase) = st;
      } else {
        ushort4 st = {f2bf(v0), f2bf(v1), f2bf(v2), f2bf(v3)};
        *(ushort4*)(outT + ((size_t)b * NL + l) * 512 + ocbase) = st;
      }
    }
  }
}

// ---------------- flash attention: dual-Q (2 q-frags/wave), split-KV x2 ----------------
// Every K/V LDS b128 read feeds TWO MFMAs -> 64 FLOP/LDS-byte (2x round-9 intensity).
#define AKVB 32
#define ATILES 32

__global__ __launch_bounds__(256, 1)
void attn_mfma(const u16* __restrict__ kq, const u16* __restrict__ vT,
               u16* __restrict__ part, float2* __restrict__ stats)
{
  __shared__ u16 ks[2][32 * 256];
  __shared__ u16 vs[2][256 * 32];

  const int fid = blockIdx.x;                 // 256 blocks = 1/CU
  const int xcd = fid & 7, idx = fid >> 3;
  const int b = (xcd << 1) | (idx & 1);
  const int rest = idx >> 1;                  // 0..15
  const int qt = rest & 7, half = rest >> 3;
  const int kvbase = half * 1024;

  const int tid = threadIdx.x;
  const int w = tid >> 6, lane = tid & 63;
  const int l31 = lane & 31, lh = lane >> 5;
  const int qb = qt * 256 + w * 64;           // wave owns q [qb, qb+64)

  const u16* kqb = kq + (size_t)b * NL * 512;
  const u16* vb  = vT + (size_t)b * NC * NL;

  auto stage = [&](int buf, int kv0) {
#pragma unroll
    for (int j = 0; j < 4; ++j) {
      const int slot = w * 256 + j * 64 + lane;
      const int r = slot >> 5, c = slot & 31;
      const int g = (c - r) & 31;
      gld16(kqb + (size_t)(kv0 + r) * 512 + g * 8, &ks[buf][(size_t)(w * 256 + j * 64) * 8]);
    }
#pragma unroll
    for (int j = 0; j < 4; ++j) {
      const int slot = w * 256 + j * 64 + lane;
      const int r = slot >> 2, c = slot & 3;
      const int g = (c - r - (r >> 2)) & 3;
      gld16(vb + (size_t)r * NL + kv0 + g * 8, &vs[buf][(size_t)(w * 256 + j * 64) * 8]);
    }
  };

  bf16x8 qfA[16], qfB[16];
  {
    const u16* qpA = kqb + (size_t)(qb + l31) * 512 + 256 + lh * 8;
    const u16* qpB = qpA + 32 * 512;
#pragma unroll
    for (int kk = 0; kk < 16; ++kk) {
      qfA[kk] = *(const bf16x8*)(qpA + kk * 16);
      qfB[kk] = *(const bf16x8*)(qpB + kk * 16);
    }
  }

  f32x16 oA[8], oB[8];
#pragma unroll
  for (int i = 0; i < 8; ++i) {
    oA[i] = (f32x16){0.f,0.f,0.f,0.f,0.f,0.f,0.f,0.f,0.f,0.f,0.f,0.f,0.f,0.f,0.f,0.f};
    oB[i] = oA[i];
  }
  float mA = -1e30f, lsA = 0.f, mB = -1e30f, lsB = 0.f;

  stage(0, kvbase);
  __syncthreads();

  for (int t = 0; t < ATILES; ++t) {
    const int cur = t & 1;
    if (t + 1 < ATILES) stage(cur ^ 1, kvbase + (t + 1) * AKVB);
    // ---- S = K*Q: each kf read feeds both q-frags ----
    const u16* kbase = &ks[cur][0];
    f32x16 sA = (f32x16){0.f,0.f,0.f,0.f,0.f,0.f,0.f,0.f,0.f,0.f,0.f,0.f,0.f,0.f,0.f,0.f};
    f32x16 sB = sA;
#pragma unroll
    for (int kk = 0; kk < 16; ++kk) {
      const int gn = 2 * kk + lh;
      const bf16x8 kf = *(const bf16x8*)(kbase + (l31 * 32 + ((gn + l31) & 31)) * 8);
      sA = __builtin_amdgcn_mfma_f32_32x32x16_bf16(kf, qfA[kk], sA, 0, 0, 0);
      sB = __builtin_amdgcn_mfma_f32_32x32x16_bf16(kf, qfB[kk], sB, 0, 0, 0);
    }
    // ---- softmax A ----
    float tm = sA[0];
#pragma unroll
    for (int i = 1; i < 16; ++i) tm = fmaxf(tm, sA[i]);
    tm = fmaxf(tm, __shfl_xor(tm, 32));
    if (!__all(tm <= mA + DEFER)) {
      const float mn = fmaxf(mA, tm);
      const float corr = ex2(mA - mn);
      mA = mn; lsA *= corr;
#pragma unroll
      for (int i = 0; i < 8; ++i) oA[i] *= corr;
    }
    float sum = 0.f;
#pragma unroll
    for (int i = 0; i < 16; ++i) { sA[i] = ex2(sA[i] - mA); sum += sA[i]; }
    sum += __shfl_xor(sum, 32);
    lsA += sum;
    // ---- softmax B ----
    tm = sB[0];
#pragma unroll
    for (int i = 1; i < 16; ++i) tm = fmaxf(tm, sB[i]);
    tm = fmaxf(tm, __shfl_xor(tm, 32));
    if (!__all(tm <= mB + DEFER)) {
      const float mn = fmaxf(mB, tm);
      const float corr = ex2(mB - mn);
      mB = mn; lsB *= corr;
#pragma unroll
      for (int i = 0; i < 8; ++i) oB[i] *= corr;
    }
    sum = 0.f;
#pragma unroll
    for (int i = 0; i < 16; ++i) { sB[i] = ex2(sB[i] - mB); sum += sB[i]; }
    sum += __shfl_xor(sum, 32);
    lsB += sum;
    // ---- pack both P tiles ----
    u32 pkA[8], pkB[8];
#pragma unroll
    for (int i = 0; i < 8; ++i) {
      pkA[i] = cvtpk(sA[2 * i], sA[2 * i + 1]);
      pkB[i] = cvtpk(sB[2 * i], sB[2 * i + 1]);
    }
    // ---- O += V*P: each vf read feeds both q-frags ----
    const u16* vbase = &vs[cur][0];
#pragma unroll
    for (int ksx = 0; ksx < 2; ++ksx) {
      const int base = ksx * 4;
      const u32 sA0 = lh ? pkA[base + 0] : pkA[base + 2];
      const u32 sA1 = lh ? pkA[base + 1] : pkA[base + 3];
      const u32 sB0 = lh ? pkB[base + 0] : pkB[base + 2];
      const u32 sB1 = lh ? pkB[base + 1] : pkB[base + 3];
      const u32 rA0 = (u32)__shfl_xor((int)sA0, 32);
      const u32 rA1 = (u32)__shfl_xor((int)sA1, 32);
      const u32 rB0 = (u32)__shfl_xor((int)sB0, 32);
      const u32 rB1 = (u32)__shfl_xor((int)sB1, 32);
      union { u32 wd[4]; bf16x8 v; } puA, puB;
      puA.wd[0] = lh ? rA0 : pkA[base + 0];
      puA.wd[1] = lh ? rA1 : pkA[base + 1];
      puA.wd[2] = lh ? pkA[base + 2] : rA0;
      puA.wd[3] = lh ? pkA[base + 3] : rA1;
      puB.wd[0] = lh ? rB0 : pkB[base + 0];
      puB.wd[1] = lh ? rB1 : pkB[base + 1];
      puB.wd[2] = lh ? pkB[base + 2] : rB0;
      puB.wd[3] = lh ? pkB[base + 3] : rB1;
      const bf16x8 pfA = puA.v, pfB = puB.v;
      const int gn = 2 * ksx + lh;
#pragma unroll
      for (int mf = 0; mf < 8; ++mf) {
        const int row = mf * 32 + l31;
        const bf16x8 vf = *(const bf16x8*)(vbase + (row * 4 + ((gn + row + (row >> 2)) & 3)) * 8);
        oA[mf] = __builtin_amdgcn_mfma_f32_32x32x16_bf16(vf, pfA, oA[mf], 0, 0, 0);
        oB[mf] = __builtin_amdgcn_mfma_f32_32x32x16_bf16(vf, pfB, oB[mf], 0, 0, 0);
      }
    }
    if (t + 1 < ATILES) __syncthreads();
  }
  // ---- store unnormalized partials + stats ----
  u16* pp = part + half * PHALF + (size_t)b * NC * NL + qb + l31;
#pragma unroll
  for (int mf = 0; mf < 8; ++mf)
#pragma unroll
    for (int r = 0; r < 16; ++r) {
      const int c = mf * 32 + (r & 3) + 8 * (r >> 2) + 4 * lh;
      pp[(size_t)c * NL] = f2bf(oA[mf][r]);
      pp[(size_t)c * NL + 32] = f2bf(oB[mf][r]);
    }
  stats[((size_t)half * NB + b) * NL + qb + lane] =
      (lane < 32) ? make_float2(mA, lsA) : make_float2(mB, lsB);
}

// ---------------- combine split-KV partials -> av fp32 + per-channel GN stats ----------
__global__ __launch_bounds__(256)
void attn_combine(const u16* __restrict__ part, const float2* __restrict__ stats,
                  float* __restrict__ av, float2* __restrict__ pstat)
{
  const int c = blockIdx.x, b = blockIdx.y;
  const int l0 = threadIdx.x * 8;
  const u16* p0 = part + ((size_t)b * NC + c) * NL + l0;
  const u16* p1 = p0 + PHALF;
  const float2* s0p = stats + (size_t)b * NL + l0;
  const float2* s1p = stats + ((size_t)NB + b) * NL + l0;
  const bf16x8 P0 = *(const bf16x8*)p0;
  const bf16x8 P1 = *(const bf16x8*)p1;
  float* op = av + ((size_t)b * NC + c) * NL + l0;
  float s = 0.f, ss = 0.f;
  float res[8];
#pragma unroll
  for (int j = 0; j < 8; ++j) {
    const float2 a = s0p[j], bb = s1p[j];
    const float M = fmaxf(a.x, bb.x);
    const float e0 = ex2(a.x - M), e1 = ex2(bb.x - M);
    const float den = 1.f / (a.y * e0 + bb.y * e1);
    const float r = (bf2f(((const u16*)&P0)[j]) * e0 + bf2f(((const u16*)&P1)[j]) * e1) * den;
    res[j] = r;
    s += r; ss += r * r;
  }
  *(float4*)op = make_float4(res[0], res[1], res[2], res[3]);
  *(float4*)(op + 4) = make_float4(res[4], res[5], res[6], res[7]);
#pragma unroll
  for (int o = 32; o > 0; o >>= 1) { s += __shfl_down(s, o); ss += __shfl_down(ss, o); }
  __shared__ float2 red[4];
  if ((threadIdx.x & 63) == 0) red[threadIdx.x >> 6] = make_float2(s, ss);
  __syncthreads();
  if (threadIdx.x == 0)
    pstat[b * 256 + c] = make_float2(red[0].x + red[1].x + red[2].x + red[3].x,
                                     red[0].y + red[1].y + red[2].y + red[3].y);
}

extern "C" void kernel_launch(void* const* d_in, const int* in_sizes, int n_in,
                              void* d_out, int out_size, void* d_ws, size_t ws_size,
                              hipStream_t stream)
{
  (void)in_sizes; (void)n_in; (void)out_size; (void)ws_size;
  const float* x        = (const float*)d_in[0];
  const float* t        = (const float*)d_in[1];
  const float* r1_gn1_w = (const float*)d_in[2];
  const float* r1_gn1_b = (const float*)d_in[3];
  const float* r1_c1_w  = (const float*)d_in[4];
  const float* r1_c1_b  = (const float*)d_in[5];
  const float* r1_gn2_w = (const float*)d_in[6];
  const float* r1_gn2_b = (const float*)d_in[7];
  const float* r1_c2_w  = (const float*)d_in[8];
  const float* r1_c2_b  = (const float*)d_in[9];
  const float* r2_gn1_w = (const float*)d_in[10];
  const float* r2_gn1_b = (const float*)d_in[11];
  const float* r2_c1_w  = (const float*)d_in[12];
  const float* r2_c1_b  = (const float*)d_in[13];
  const float* r2_gn2_w = (const float*)d_in[14];
  const float* r2_gn2_b = (const float*)d_in[15];
  const float* r2_c2_w  = (const float*)d_in[16];
  const float* r2_c2_b  = (const float*)d_in[17];
  const float* lin_w    = (const float*)d_in[18];
  const float* lin_b    = (const float*)d_in[19];

  float* out = (float*)d_out;

  const size_t TSZ = (size_t)NB * TROWS * 256 * 2;           // 16,793,600
  u16* tA  = (u16*)d_ws;
  u16* tB  = (u16*)((char*)d_ws + TSZ);
  u16* kq  = tB;                                             // spans [TSZ, 3TSZ)
  float* avF = (float*)((char*)d_ws + TSZ);
  u16* tC  = (u16*)((char*)d_ws + 3 * TSZ);
  u16* vT  = tC;
  u16* Wp  = (u16*)((char*)d_ws + 4 * TSZ);
  u16* Wq  = Wp + 4 * 196608;
  float* bq = (float*)(Wq + 196608);
  float2* pstat = (float2*)((char*)bq + 4096);

  const dim3 gPack(768, 5);
  const dim3 gC(16, 2, NB);
  const dim3 gQ(16, 6, NB);
  const dim3 gS16(16, NB);
  const dim3 gA64(64, NB);
  const dim3 gCmb(NC, NB);

  pack_w<<<gPack, 256, 0, stream>>>(r1_c1_w, r1_c2_w, r2_c1_w, r2_c2_w, lin_w, lin_b, Wp, Wq, bq);

  // res1
  stats_f32<<<NB * NC, 256, 0, stream>>>(x, pstat);
  apply_f32T<<<gA64, 256, 0, stream>>>(x, pstat, r1_gn1_w, r1_gn1_b, tA);
  conv_mfma<256, 3, true, 0><<<gC, 256, 0, stream>>>(tA, Wp, r1_c1_b, t, tB, nullptr, nullptr, nullptr);
  stats_T<<<gS16, 256, 0, stream>>>(tB, pstat);
  apply_TT<<<gS16, 256, 0, stream>>>(tB, pstat, r1_gn2_w, r1_gn2_b, tC);
  conv_mfma<256, 3, false, 1><<<gC, 256, 0, stream>>>(tC, Wp + 196608, r1_c2_b, nullptr, tA, nullptr, x, nullptr);

  // attention
  conv_mfma<768, 1, false, 0><<<gQ, 256, 0, stream>>>(tA, Wq, bq, nullptr, kq, vT, nullptr, nullptr);
  attn_mfma<<<256, 256, 0, stream>>>(kq, vT, (u16*)out, (float2*)tA);
  attn_combine<<<gCmb, 256, 0, stream>>>((const u16*)out, (const float2*)tA, avF, pstat);

  // res2
  apply_f32T<<<gA64, 256, 0, stream>>>(avF, pstat, r2_gn1_w, r2_gn1_b, tA);
  conv_mfma<256, 3, true, 0><<<gC, 256, 0, stream>>>(tA, Wp + 2 * 196608, r2_c1_b, t, tC, nullptr, nullptr, nullptr);
  stats_T<<<gS16, 256, 0, stream>>>(tC, pstat);
  apply_TT<<<gS16, 256, 0, stream>>>(tC, pstat, r2_gn2_w, r2_gn2_b, tA);
  conv_mfma<256, 3, false, 2><<<gC, 256, 0, stream>>>(tA, Wp + 3 * 196608, r2_c2_b, nullptr, nullptr, nullptr, avF, out);
}

// Round 11
// 357.166 us; speedup vs baseline: 2.4200x; 2.4200x over previous
//
#include <hip/hip_runtime.h>

typedef unsigned short u16;
typedef unsigned int u32;
typedef __attribute__((ext_vector_type(8))) short bf16x8;
typedef __attribute__((ext_vector_type(4))) float f32x4;
typedef __attribute__((ext_vector_type(16))) float f32x16;

#define NB 16
#define NC 256
#define NL 2048
#define EPS 1e-5f
#define QSC2 0.0901684401f   // (1/sqrt(256)) * log2(e)
#define DEFER 11.54f         // 8 * log2(e)
#define TROWS 2050
#define PHALF ((size_t)NB * NC * NL)

__device__ __forceinline__ float bf2f(u16 a) {
  union { unsigned u; float f; } v; v.u = (unsigned)a << 16; return v.f;
}
__device__ __forceinline__ u16 f2bf(float f) {
  union { float f; unsigned u; } v; v.f = f;
  return (u16)((v.u + 0x7fffu + ((v.u >> 16) & 1u)) >> 16);
}
__device__ __forceinline__ u32 cvtpk(float lo, float hi) {
  u32 r;
  asm("v_cvt_pk_bf16_f32 %0, %1, %2" : "=v"(r) : "v"(lo), "v"(hi));
  return r;
}
__device__ __forceinline__ float ex2(float x) {
  float r;
  asm("v_exp_f32 %0, %1" : "=v"(r) : "v"(x));
  return r;
}
__device__ __forceinline__ void gld16(const void* gsrc, void* ldst) {
  __builtin_amdgcn_global_load_lds(
      (const __attribute__((address_space(1))) void*)gsrc,
      (__attribute__((address_space(3))) void*)ldst, 16, 0, 0);
}

// ---------------- weight pack ----------------
__global__ __launch_bounds__(256)
void pack_w(const float* __restrict__ w1, const float* __restrict__ w2,
            const float* __restrict__ w3, const float* __restrict__ w4,
            const float* __restrict__ lw, const float* __restrict__ lb,
            u16* __restrict__ Wp, u16* __restrict__ Wq, float* __restrict__ bq)
{
  const int a = blockIdx.y;
  const int gid = blockIdx.x * 256 + threadIdx.x;
  if (a < 4) {
    const float* w = a == 0 ? w1 : a == 1 ? w2 : a == 2 ? w3 : w4;
    const int d = gid >> 16, rem = gid & 65535;
    const int oc = rem >> 8, ic = rem & 255;
    Wp[a * 196608 + gid] = f2bf(w[(oc * 256 + ic) * 3 + d]);
  } else {
    const int oc = gid >> 8;
    const float s = (oc >= 256 && oc < 512) ? QSC2 : 1.0f;
    Wq[gid] = f2bf(lw[gid] * s);
    if (gid < 768) bq[gid] = lb[gid] * ((gid >= 256 && gid < 512) ? QSC2 : 1.0f);
  }
}

// ---------------- GN stats: fp32 (C,L) -> pstat[b*256+c] ----
__global__ __launch_bounds__(256)
void stats_f32(const float* __restrict__ x, float2* __restrict__ pstat)
{
  const int blk = blockIdx.x;
  const float* p = x + (size_t)blk * NL + threadIdx.x * 8;
  const float4 a = ((const float4*)p)[0];
  const float4 c4 = ((const float4*)p)[1];
  float s = (a.x + a.y) + (a.z + a.w) + (c4.x + c4.y) + (c4.z + c4.w);
  float ss = a.x*a.x + a.y*a.y + a.z*a.z + a.w*a.w + c4.x*c4.x + c4.y*c4.y + c4.z*c4.z + c4.w*c4.w;
#pragma unroll
  for (int o = 32; o > 0; o >>= 1) { s += __shfl_down(s, o); ss += __shfl_down(ss, o); }
  __shared__ float2 red[4];
  if ((threadIdx.x & 63) == 0) red[threadIdx.x >> 6] = make_float2(s, ss);
  __syncthreads();
  if (threadIdx.x == 0)
    pstat[blk] = make_float2(red[0].x + red[1].x + red[2].x + red[3].x,
                             red[0].y + red[1].y + red[2].y + red[3].y);
}

// ---------------- GN apply: fp32 (C,L) -> bf16 T padded (bank-aware transpose) ----
__global__ __launch_bounds__(256)
void apply_f32T(const float* __restrict__ x, const float2* __restrict__ pstat,
                const float* __restrict__ gw, const float* __restrict__ gb,
                u16* __restrict__ outT)
{
  __shared__ float2 chs[256];
  __shared__ float gm[32], gi[32];
  __shared__ float ta[32][257];
  const int t = threadIdx.x, b = blockIdx.y;
  const int L0 = blockIdx.x * 32;
  chs[t] = pstat[b * 256 + t];
  __syncthreads();
  if (t < 32) {
    float S = 0.f, SS = 0.f;
#pragma unroll
    for (int j = 0; j < 8; ++j) { S += chs[t * 8 + j].x; SS += chs[t * 8 + j].y; }
    const float mean = S * (1.f / 16384.f);
    const float var = SS * (1.f / 16384.f) - mean * mean;
    gm[t] = mean; gi[t] = rsqrtf(var + EPS);
  }
  {
    const int cR = t >> 3, lq = (t & 7) * 4;
#pragma unroll
    for (int i = 0; i < 8; ++i) {
      const int c = i * 32 + cR;
      const float4 v = *(const float4*)&x[((size_t)b * NC + c) * NL + L0 + lq];
      ta[lq + 0][c] = v.x; ta[lq + 1][c] = v.y; ta[lq + 2][c] = v.z; ta[lq + 3][c] = v.w;
    }
  }
  __syncthreads();
  const int g = t & 31, rbase = t >> 5;
  float ga[8], be[8];
#pragma unroll
  for (int j = 0; j < 4; ++j)
#pragma unroll
    for (int k = 0; k < 2; ++k) {
      const int c = 2 * g + 64 * j + k;
      const int grp = c >> 3;
      ga[j * 2 + k] = gw[c] * gi[grp];
      be[j * 2 + k] = gb[c] - gm[grp] * ga[j * 2 + k];
    }
#pragma unroll
  for (int ri = 0; ri < 4; ++ri) {
    const int row = rbase + ri * 8;
    u16* orow = outT + ((size_t)b * TROWS + 1 + L0 + row) * 256;
#pragma unroll
    for (int j = 0; j < 4; ++j) {
      const int c = 2 * g + 64 * j;
      const float v0 = ta[row][c], v1 = ta[row][c + 1];
      ushort2 o;
      o.x = f2bf(fmaxf(fmaf(v0, ga[j * 2], be[j * 2]), 0.f));
      o.y = f2bf(fmaxf(fmaf(v1, ga[j * 2 + 1], be[j * 2 + 1]), 0.f));
      *(ushort2*)(orow + c) = o;
    }
  }
  if (blockIdx.x == 0 && t < 128) {
    const int r = (t >> 6) ? 2049 : 0;
    *(ushort4*)(outT + ((size_t)b * TROWS + r) * 256 + (t & 63) * 4) = (ushort4){0, 0, 0, 0};
  }
}

// ---------------- GN apply: bf16 T -> bf16 T padded ----
__global__ __launch_bounds__(256)
void apply_TT(const u16* __restrict__ inT, const float2* __restrict__ pstat,
              const float* __restrict__ gw, const float* __restrict__ gb,
              u16* __restrict__ outT)
{
  __shared__ float2 chs[256];
  __shared__ float gm[32], gi[32];
  const int t = threadIdx.x, b = blockIdx.y;
  {
    float S = 0.f, SS = 0.f;
#pragma unroll
    for (int p = 0; p < 16; ++p) {
      const float2 v = pstat[((size_t)b * 16 + p) * 256 + t];
      S += v.x; SS += v.y;
    }
    chs[t] = make_float2(S, SS);
  }
  __syncthreads();
  if (t < 32) {
    float S = 0.f, SS = 0.f;
#pragma unroll
    for (int j = 0; j < 8; ++j) { S += chs[t * 8 + j].x; SS += chs[t * 8 + j].y; }
    const float mean = S * (1.f / 16384.f);
    const float var = SS * (1.f / 16384.f) - mean * mean;
    gm[t] = mean; gi[t] = rsqrtf(var + EPS);
  }
  __syncthreads();
  const int g = t & 31;
  float ga[8], be[8];
#pragma unroll
  for (int j = 0; j < 8; ++j) {
    ga[j] = gw[g * 8 + j] * gi[g];
    be[j] = gb[g * 8 + j] - gm[g] * ga[j];
  }
#pragma unroll
  for (int j = 0; j < 16; ++j) {
    const int row = blockIdx.x * 128 + j * 8 + (t >> 5);
    const size_t off = ((size_t)b * TROWS + 1 + row) * 256 + g * 8;
    const bf16x8 h = *(const bf16x8*)(inT + off);
    u16 o[8];
#pragma unroll
    for (int i = 0; i < 8; ++i)
      o[i] = f2bf(fmaxf(fmaf(bf2f(((const u16*)&h)[i]), ga[i], be[i]), 0.f));
    *(bf16x8*)(outT + off) = *(bf16x8*)o;
  }
  if (blockIdx.x == 0 && t < 128) {
    const int r = (t >> 6) ? 2049 : 0;
    *(ushort4*)(outT + ((size_t)b * TROWS + r) * 256 + (t & 63) * 4) = (ushort4){0, 0, 0, 0};
  }
}

// ---------------- conv GEMM via MFMA ----------------
// RESM 0: bf16 T out (or kq/vT for OCT=768); RESM 1: bf16 T = conv+resf; RESM 2: fp32 = conv+resf
// STATS: fuse per-channel GN partial sums into epilogue -> pstatOut[(b*16+lbx)*256+oc]
template<int OCT, int KD, bool HAS_T, int RESM, bool STATS>
__global__ __launch_bounds__(256, 2)
void conv_mfma(const u16* __restrict__ xT, const u16* __restrict__ Wp,
               const float* __restrict__ bias, const float* __restrict__ tadd,
               u16* __restrict__ outT, u16* __restrict__ vTout,
               const float* __restrict__ resf, float* __restrict__ outf,
               float2* __restrict__ pstatOut)
{
  constexpr int DOFF = (KD == 3) ? 0 : 1;
  __shared__ __align__(16) u16 xs[2][130 * 128];
  const int lb = blockIdx.x * 128;
  const int ocb = blockIdx.y * 128;
  const int b = blockIdx.z;
  const int tid = threadIdx.x;
  const int w = tid >> 6, lane = tid & 63;
  const int l15 = lane & 15, lg = lane >> 4;
  const int woc = (w >> 1) * 64, wl = (w & 1) * 64;

  f32x4 acc[4][4];
#pragma unroll
  for (int i = 0; i < 4; ++i)
#pragma unroll
    for (int j = 0; j < 4; ++j) acc[i][j] = (f32x4){0.f, 0.f, 0.f, 0.f};

  const u16* xTb = xT + ((size_t)b * TROWS + lb) * 256;

  auto stageX = [&](int buf, int ich) {
    u16* xb = &xs[buf][0];
#pragma unroll
    for (int j = 0; j < 8; ++j) {
      const int slot = w * 512 + j * 64 + lane;
      const int row = slot >> 4, g0 = slot & 15;
      const int g = (g0 & 8) | ((g0 ^ row) & 7);
      gld16(xTb + (size_t)row * 256 + ich * 128 + g * 8, xb + (size_t)(w * 512 + j * 64) * 8);
    }
    if (w == 0 && lane < 32) {
      const int slot = 2048 + lane;
      const int row = slot >> 4, g0 = slot & 15;
      const int g = (g0 & 8) | ((g0 ^ row) & 7);
      gld16(xTb + (size_t)row * 256 + ich * 128 + g * 8, xb + (size_t)2048 * 8);
    }
  };
  auto loadW = [&](bf16x8 (&af)[KD][4], int p) {
    const int ich = p >> 2, kc = p & 3;
#pragma unroll
    for (int d = 0; d < KD; ++d)
#pragma unroll
      for (int mf = 0; mf < 4; ++mf)
        af[d][mf] = *(const bf16x8*)(Wp + ((size_t)d * OCT + ocb + woc + mf * 16 + l15) * 256
                                        + ich * 128 + kc * 32 + lg * 8);
  };

  bf16x8 afbuf[2][KD][4];
  stageX(0, 0);
  loadW(afbuf[0], 0);
  __syncthreads();
  stageX(1, 1);

#pragma unroll
  for (int p = 0; p < 8; ++p) {
    if (p == 4) __syncthreads();
    if (p < 7) loadW(afbuf[(p + 1) & 1], p + 1);
    const int kc = p & 3;
    const int gg = kc * 4 + lg;
    const char* xb = (const char*)&xs[p >> 2][0];
#pragma unroll
    for (int nf = 0; nf < 4; ++nf) {
#pragma unroll
      for (int d = 0; d < KD; ++d) {
        const int r = wl + nf * 16 + l15 + d + DOFF;
        const int gsr = (gg & 8) | ((gg ^ r) & 7);
        const bf16x8 bf = *(const bf16x8*)(xb + r * 256 + gsr * 16);
#pragma unroll
        for (int mf = 0; mf < 4; ++mf)
          acc[mf][nf] = __builtin_amdgcn_mfma_f32_16x16x32_bf16(afbuf[p & 1][d][mf], bf, acc[mf][nf], 0, 0, 0);
      }
    }
  }

  if (OCT == 768 && ocb >= 512) {
    __syncthreads();
    u16* tile = (u16*)&xs[0][0];   // [128][136]
#pragma unroll
    for (int mf = 0; mf < 4; ++mf) {
      const int cl = woc + mf * 16 + lg * 4;
      const float4 bv = *(const float4*)&bias[ocb + cl];
#pragma unroll
      for (int nf = 0; nf < 4; ++nf) {
        const int ll = wl + nf * 16 + l15;
        const f32x4 a = acc[mf][nf];
        tile[(cl + 0) * 136 + ll] = f2bf(a[0] + bv.x);
        tile[(cl + 1) * 136 + ll] = f2bf(a[1] + bv.y);
        tile[(cl + 2) * 136 + ll] = f2bf(a[2] + bv.z);
        tile[(cl + 3) * 136 + ll] = f2bf(a[3] + bv.w);
      }
    }
    __syncthreads();
    const int cv0 = ocb - 512;
#pragma unroll
    for (int it = 0; it < 8; ++it) {
      const int chunk = it * 256 + tid;
      const int row = chunk >> 4, off = (chunk & 15) * 8;
      const bf16x8 v = *(const bf16x8*)&tile[row * 136 + off];
      *(bf16x8*)(vTout + ((size_t)b * NC + cv0 + row) * NL + lb + off) = v;
    }
    return;
  }

  float cs[4][4], cq[4][4];
  if (STATS) {
#pragma unroll
    for (int i = 0; i < 4; ++i)
#pragma unroll
      for (int j = 0; j < 4; ++j) { cs[i][j] = 0.f; cq[i][j] = 0.f; }
  }

#pragma unroll
  for (int mf = 0; mf < 4; ++mf) {
    const int ocbase = ocb + woc + mf * 16 + lg * 4;
    float4 bv = *(const float4*)&bias[ocbase];
    if (HAS_T) {
      const float4 tv = *(const float4*)&tadd[b * 256 + ocbase];
      bv.x += tv.x; bv.y += tv.y; bv.z += tv.z; bv.w += tv.w;
    }
#pragma unroll
    for (int nf = 0; nf < 4; ++nf) {
      const int l = lb + wl + nf * 16 + l15;
      const f32x4 a = acc[mf][nf];
      float v0 = a[0] + bv.x, v1 = a[1] + bv.y, v2 = a[2] + bv.z, v3 = a[3] + bv.w;
      if (RESM >= 1) {
        const float* rp = resf + ((size_t)b * NC + ocbase) * NL + l;
        v0 += rp[0]; v1 += rp[NL]; v2 += rp[2 * (size_t)NL]; v3 += rp[3 * (size_t)NL];
      }
      if (STATS) {
        cs[mf][0] += v0; cq[mf][0] += v0 * v0;
        cs[mf][1] += v1; cq[mf][1] += v1 * v1;
        cs[mf][2] += v2; cq[mf][2] += v2 * v2;
        cs[mf][3] += v3; cq[mf][3] += v3 * v3;
      }
      if (RESM == 2) {
        float* op = outf + ((size_t)b * NC + ocbase) * NL + l;
        op[0] = v0; op[NL] = v1; op[2 * (size_t)NL] = v2; op[3 * (size_t)NL] = v3;
      } else if (OCT == 256) {
        ushort4 st = {f2bf(v0), f2bf(v1), f2bf(v2), f2bf(v3)};
        *(ushort4*)(outT + ((size_t)b * TROWS + 1 + l) * 256 + ocbase) = st;
      } else {
        ushort4 st = {f2bf(v0), f2bf(v1), f2bf(v2), f2bf(v3)};
        *(ushort4*)(outT + ((size_t)b * NL + l) * 512 + ocbase) = st;
      }
    }
  }

  if (STATS) {
    // per-channel partials over this block's 128 rows; block owns (b, lbx, ocb..+128) exclusively
    __syncthreads();                       // all reads of xs done
    float* sred = (float*)&xs[0][0];       // [0..255]=sum halves, [256..511]=sq halves
#pragma unroll
    for (int mf = 0; mf < 4; ++mf)
#pragma unroll
      for (int j = 0; j < 4; ++j) {
        float s = cs[mf][j], q = cq[mf][j];
#pragma unroll
        for (int m = 1; m < 16; m <<= 1) { s += __shfl_xor(s, m); q += __shfl_xor(q, m); }
        if (l15 == 0) {
          const int cl = woc + mf * 16 + lg * 4 + j;
          sred[(w & 1) * 128 + cl] = s;
          sred[256 + (w & 1) * 128 + cl] = q;
        }
      }
    __syncthreads();
    if (tid < 128) {
      const float s = sred[tid] + sred[128 + tid];
      const float q = sred[256 + tid] + sred[384 + tid];
      pstatOut[((size_t)b * 16 + blockIdx.x) * 256 + ocb + tid] = make_float2(s, q);
    }
  }
}

// ---------------- flash attention: split-KV x2, r9 version (measured 116 us) ----------------
#define AKVB 32
#define ATILES 32

__global__ __launch_bounds__(256, 2)
void attn_mfma(const u16* __restrict__ kq, const u16* __restrict__ vT,
               u16* __restrict__ part, float2* __restrict__ stats)
{
  __shared__ u16 ks[2][32 * 256];
  __shared__ u16 vs[2][256 * 32];

  const int fid = blockIdx.x;
  const int xcd = fid & 7, idx = fid >> 3;
  const int b = (xcd << 1) | (idx & 1);
  const int rest = idx >> 1;
  const int qt = rest & 15, half = rest >> 4;
  const int kvbase = half * 1024;

  const int tid = threadIdx.x;
  const int w = tid >> 6, lane = tid & 63;
  const int l31 = lane & 31, lh = lane >> 5;
  const int q = qt * 128 + w * 32 + l31;

  const u16* kqb = kq + (size_t)b * NL * 512;
  const u16* vb  = vT + (size_t)b * NC * NL;

  auto stage = [&](int buf, int kv0) {
#pragma unroll
    for (int j = 0; j < 4; ++j) {
      const int slot = w * 256 + j * 64 + lane;
      const int r = slot >> 5, c = slot & 31;
      const int g = (c - r) & 31;
      gld16(kqb + (size_t)(kv0 + r) * 512 + g * 8, &ks[buf][(size_t)(w * 256 + j * 64) * 8]);
    }
#pragma unroll
    for (int j = 0; j < 4; ++j) {
      const int slot = w * 256 + j * 64 + lane;
      const int r = slot >> 2, c = slot & 3;
      const int g = (c - r - (r >> 2)) & 3;
      gld16(vb + (size_t)r * NL + kv0 + g * 8, &vs[buf][(size_t)(w * 256 + j * 64) * 8]);
    }
  };

  bf16x8 qf[16];
  {
    const u16* qp = kqb + (size_t)q * 512 + 256 + lh * 8;
#pragma unroll
    for (int kk = 0; kk < 16; ++kk) qf[kk] = *(const bf16x8*)(qp + kk * 16);
  }

  f32x16 o[8];
#pragma unroll
  for (int i = 0; i < 8; ++i)
    o[i] = (f32x16){0.f,0.f,0.f,0.f,0.f,0.f,0.f,0.f,0.f,0.f,0.f,0.f,0.f,0.f,0.f,0.f};
  float m = -1e30f, lsum = 0.f;

  stage(0, kvbase);
  __syncthreads();

  for (int t = 0; t < ATILES; ++t) {
    const int cur = t & 1;
    if (t + 1 < ATILES) stage(cur ^ 1, kvbase + (t + 1) * AKVB);
    const u16* kbase = &ks[cur][0];
    f32x16 s = (f32x16){0.f,0.f,0.f,0.f,0.f,0.f,0.f,0.f,0.f,0.f,0.f,0.f,0.f,0.f,0.f,0.f};
#pragma unroll
    for (int kk = 0; kk < 16; ++kk) {
      const int gn = 2 * kk + lh;
      const bf16x8 kf = *(const bf16x8*)(kbase + (l31 * 32 + ((gn + l31) & 31)) * 8);
      s = __builtin_amdgcn_mfma_f32_32x32x16_bf16(kf, qf[kk], s, 0, 0, 0);
    }
    float tm = s[0];
#pragma unroll
    for (int i = 1; i < 16; ++i) tm = fmaxf(tm, s[i]);
    tm = fmaxf(tm, __shfl_xor(tm, 32));
    if (!__all(tm <= m + DEFER)) {
      const float mn = fmaxf(m, tm);
      const float corr = ex2(m - mn);
      m = mn; lsum *= corr;
#pragma unroll
      for (int i = 0; i < 8; ++i) o[i] *= corr;
    }
    float sum = 0.f;
#pragma unroll
    for (int i = 0; i < 16; ++i) { s[i] = ex2(s[i] - m); sum += s[i]; }
    sum += __shfl_xor(sum, 32);
    lsum += sum;
    u32 pk[8];
#pragma unroll
    for (int i = 0; i < 8; ++i) pk[i] = cvtpk(s[2 * i], s[2 * i + 1]);
    const u16* vbase = &vs[cur][0];
#pragma unroll
    for (int ksx = 0; ksx < 2; ++ksx) {
      const int base = ksx * 4;
      const u32 send0 = lh ? pk[base + 0] : pk[base + 2];
      const u32 send1 = lh ? pk[base + 1] : pk[base + 3];
      const u32 r0 = (u32)__shfl_xor((int)send0, 32);
      const u32 r1 = (u32)__shfl_xor((int)send1, 32);
      union { u32 wd[4]; bf16x8 v; } pu;
      pu.wd[0] = lh ? r0 : pk[base + 0];
      pu.wd[1] = lh ? r1 : pk[base + 1];
      pu.wd[2] = lh ? pk[base + 2] : r0;
      pu.wd[3] = lh ? pk[base + 3] : r1;
      const bf16x8 pf = pu.v;
      const int gn = 2 * ksx + lh;
#pragma unroll
      for (int mf = 0; mf < 8; ++mf) {
        const int row = mf * 32 + l31;
        const bf16x8 vf = *(const bf16x8*)(vbase + (row * 4 + ((gn + row + (row >> 2)) & 3)) * 8);
        o[mf] = __builtin_amdgcn_mfma_f32_32x32x16_bf16(vf, pf, o[mf], 0, 0, 0);
      }
    }
    if (t + 1 < ATILES) __syncthreads();
  }
  u16* pp = part + half * PHALF + (size_t)b * NC * NL + q;
#pragma unroll
  for (int mf = 0; mf < 8; ++mf)
#pragma unroll
    for (int r = 0; r < 16; ++r) {
      const int c = mf * 32 + (r & 3) + 8 * (r >> 2) + 4 * lh;
      pp[(size_t)c * NL] = f2bf(o[mf][r]);
    }
  if (lane < 32)
    stats[((size_t)half * NB + b) * NL + q] = make_float2(m, lsum);
}

// ---------------- combine split-KV partials -> av fp32 + per-channel GN stats ----------
__global__ __launch_bounds__(256)
void attn_combine(const u16* __restrict__ part, const float2* __restrict__ stats,
                  float* __restrict__ av, float2* __restrict__ pstat)
{
  const int c = blockIdx.x, b = blockIdx.y;
  const int l0 = threadIdx.x * 8;
  const u16* p0 = part + ((size_t)b * NC + c) * NL + l0;
  const u16* p1 = p0 + PHALF;
  const float2* s0p = stats + (size_t)b * NL + l0;
  const float2* s1p = stats + ((size_t)NB + b) * NL + l0;
  const bf16x8 P0 = *(const bf16x8*)p0;
  const bf16x8 P1 = *(const bf16x8*)p1;
  float* op = av + ((size_t)b * NC + c) * NL + l0;
  float s = 0.f, ss = 0.f;
  float res[8];
#pragma unroll
  for (int j = 0; j < 8; ++j) {
    const float2 a = s0p[j], bb = s1p[j];
    const float M = fmaxf(a.x, bb.x);
    const float e0 = ex2(a.x - M), e1 = ex2(bb.x - M);
    const float den = 1.f / (a.y * e0 + bb.y * e1);
    const float r = (bf2f(((const u16*)&P0)[j]) * e0 + bf2f(((const u16*)&P1)[j]) * e1) * den;
    res[j] = r;
    s += r; ss += r * r;
  }
  *(float4*)op = make_float4(res[0], res[1], res[2], res[3]);
  *(float4*)(op + 4) = make_float4(res[4], res[5], res[6], res[7]);
#pragma unroll
  for (int o = 32; o > 0; o >>= 1) { s += __shfl_down(s, o); ss += __shfl_down(ss, o); }
  __shared__ float2 red[4];
  if ((threadIdx.x & 63) == 0) red[threadIdx.x >> 6] = make_float2(s, ss);
  __syncthreads();
  if (threadIdx.x == 0)
    pstat[b * 256 + c] = make_float2(red[0].x + red[1].x + red[2].x + red[3].x,
                                     red[0].y + red[1].y + red[2].y + red[3].y);
}

extern "C" void kernel_launch(void* const* d_in, const int* in_sizes, int n_in,
                              void* d_out, int out_size, void* d_ws, size_t ws_size,
                              hipStream_t stream)
{
  (void)in_sizes; (void)n_in; (void)out_size; (void)ws_size;
  const float* x        = (const float*)d_in[0];
  const float* t        = (const float*)d_in[1];
  const float* r1_gn1_w = (const float*)d_in[2];
  const float* r1_gn1_b = (const float*)d_in[3];
  const float* r1_c1_w  = (const float*)d_in[4];
  const float* r1_c1_b  = (const float*)d_in[5];
  const float* r1_gn2_w = (const float*)d_in[6];
  const float* r1_gn2_b = (const float*)d_in[7];
  const float* r1_c2_w  = (const float*)d_in[8];
  const float* r1_c2_b  = (const float*)d_in[9];
  const float* r2_gn1_w = (const float*)d_in[10];
  const float* r2_gn1_b = (const float*)d_in[11];
  const float* r2_c1_w  = (const float*)d_in[12];
  const float* r2_c1_b  = (const float*)d_in[13];
  const float* r2_gn2_w = (const float*)d_in[14];
  const float* r2_gn2_b = (const float*)d_in[15];
  const float* r2_c2_w  = (const float*)d_in[16];
  const float* r2_c2_b  = (const float*)d_in[17];
  const float* lin_w    = (const float*)d_in[18];
  const float* lin_b    = (const float*)d_in[19];

  float* out = (float*)d_out;

  const size_t TSZ = (size_t)NB * TROWS * 256 * 2;           // 16,793,600
  u16* tA  = (u16*)d_ws;
  u16* tB  = (u16*)((char*)d_ws + TSZ);
  u16* kq  = tB;                                             // spans [TSZ, 3TSZ)
  float* avF = (float*)((char*)d_ws + TSZ);
  u16* tC  = (u16*)((char*)d_ws + 3 * TSZ);
  u16* vT  = tC;
  u16* Wp  = (u16*)((char*)d_ws + 4 * TSZ);
  u16* Wq  = Wp + 4 * 196608;
  float* bq = (float*)(Wq + 196608);
  float2* pstat = (float2*)((char*)bq + 4096);

  const dim3 gPack(768, 5);
  const dim3 gC(16, 2, NB);
  const dim3 gQ(16, 6, NB);
  const dim3 gS16(16, NB);
  const dim3 gA64(64, NB);
  const dim3 gCmb(NC, NB);

  pack_w<<<gPack, 256, 0, stream>>>(r1_c1_w, r1_c2_w, r2_c1_w, r2_c2_w, lin_w, lin_b, Wp, Wq, bq);

  // res1: stats(x); gn1-apply; conv1 (+fused gn2 stats); gn2-apply; conv2 (+x residual)
  stats_f32<<<NB * NC, 256, 0, stream>>>(x, pstat);
  apply_f32T<<<gA64, 256, 0, stream>>>(x, pstat, r1_gn1_w, r1_gn1_b, tA);
  conv_mfma<256, 3, true, 0, true><<<gC, 256, 0, stream>>>(tA, Wp, r1_c1_b, t, tB, nullptr, nullptr, nullptr, pstat);
  apply_TT<<<gS16, 256, 0, stream>>>(tB, pstat, r1_gn2_w, r1_gn2_b, tC);
  conv_mfma<256, 3, false, 1, false><<<gC, 256, 0, stream>>>(tC, Wp + 196608, r1_c2_b, nullptr, tA, nullptr, x, nullptr, nullptr);

  // attention
  conv_mfma<768, 1, false, 0, false><<<gQ, 256, 0, stream>>>(tA, Wq, bq, nullptr, kq, vT, nullptr, nullptr, nullptr);
  attn_mfma<<<512, 256, 0, stream>>>(kq, vT, (u16*)out, (float2*)tA);
  attn_combine<<<gCmb, 256, 0, stream>>>((const u16*)out, (const float2*)tA, avF, pstat);

  // res2
  apply_f32T<<<gA64, 256, 0, stream>>>(avF, pstat, r2_gn1_w, r2_gn1_b, tA);
  conv_mfma<256, 3, true, 0, true><<<gC, 256, 0, stream>>>(tA, Wp + 2 * 196608, r2_c1_b, t, tC, nullptr, nullptr, nullptr, pstat);
  apply_TT<<<gS16, 256, 0, stream>>>(tC, pstat, r2_gn2_w, r2_gn2_b, tA);
  conv_mfma<256, 3, false, 2, false><<<gC, 256, 0, stream>>>(tA, Wp + 3 * 196608, r2_c2_b, nullptr, nullptr, nullptr, avF, out, nullptr);
}